// Round 10
// baseline (5308.916 us; speedup 1.0000x reference)
//
#include <hip/hip_runtime.h>
#include <math.h>
#include <stdint.h>

#define BATCH 128
#define NF 49
#define EDIM 2048
#define EMBD 512
#define DDIM 512
#define VOC 12000
#define VOCP 12032
#define TT 21
#define G4 2048   // 4*D
#define UWN 2560  // 512 + 2048

typedef __bf16 bf16x8 __attribute__((ext_vector_type(8)));
typedef float f32x4 __attribute__((ext_vector_type(4)));
typedef unsigned short ushortx8 __attribute__((ext_vector_type(8)));
typedef unsigned short u16;

union U8 { ushortx8 u; bf16x8 b; };

__device__ __forceinline__ u16 bf16_rne(float x) {
    union { float f; unsigned u; } v; v.f = x;
    unsigned r = v.u + 0x7fffu + ((v.u >> 16) & 1u);
    return (u16)(r >> 16);
}
__device__ __forceinline__ float bf16_to_f(u16 h) {
    union { unsigned u; float f; } v; v.u = ((unsigned)h) << 16;
    return v.f;
}
__device__ __forceinline__ float sigmoidf(float x) { return 1.f / (1.f + expf(-x)); }

__device__ __forceinline__ void gload16(const void* g, void* l) {
    auto gp = reinterpret_cast<const __attribute__((address_space(1))) unsigned int*>(
        reinterpret_cast<uintptr_t>(g));
    auto lp = reinterpret_cast<__attribute__((address_space(3))) unsigned int*>(
        reinterpret_cast<uintptr_t>(l));
    __builtin_amdgcn_global_load_lds(gp, lp, 16, 0, 0);
}

// =======================================================================
// pre-split bf16x3 GEMM (proven R6): C = A*W^T (+bias), hi/lo bf16 inputs
// =======================================================================
__global__ __launch_bounds__(256) void gemm_bf16s(
    const u16* __restrict__ Ahi, const u16* __restrict__ Alo, int lda,
    const u16* __restrict__ Whi, const u16* __restrict__ Wlo, int ldw,
    float* __restrict__ C, int ldc,
    const float* __restrict__ bias,
    int Nn, int K)
{
    __shared__ u16 Ah[128 * 32];
    __shared__ u16 Al[128 * 32];
    __shared__ u16 Wh[128 * 32];
    __shared__ u16 Wl[128 * 32];

    const int nbx = gridDim.x;
    const int nwg = nbx * gridDim.y;
    const int orig = blockIdx.y * nbx + blockIdx.x;
    const int q = nwg >> 3, r = nwg & 7;
    const int xcd = orig & 7, pos = orig >> 3;
    const int swz = (xcd < r ? xcd * (q + 1) : r * (q + 1) + (xcd - r) * q) + pos;
    const int by = swz / nbx, bx = swz - by * nbx;

    const int bm = by * 128;
    const int bn = bx * 128;
    const int tid = threadIdx.x;
    const int lane = tid & 63;
    const int wid = tid >> 6;
    const int wr = (wid >> 1) * 64;
    const int wc = (wid & 1) * 64;

    const int srow = wid * 32 + (lane >> 2);
    const int sslot = (lane & 3) ^ ((lane >> 2) & 3);
    const u16* a_src = Ahi + (size_t)(bm + srow) * lda + sslot * 8;
    const u16* al_src = Alo + (size_t)(bm + srow) * lda + sslot * 8;
    const u16* w_src = Whi + (size_t)(bn + srow) * ldw + sslot * 8;
    const u16* wl_src = Wlo + (size_t)(bn + srow) * ldw + sslot * 8;
    const int lds_base = (wid * 32) * 32;

    const int fr = lane & 15;
    const int ksl = lane >> 4;
    const int rsl = (ksl ^ (fr & 3)) * 8;

    f32x4 acc[4][4] = {};

    for (int k0 = 0; k0 < K; k0 += 32) {
        #pragma unroll
        for (int cch = 0; cch < 2; ++cch) {
            const size_t go = (size_t)cch * 16 * lda + k0;
            const size_t gw = (size_t)cch * 16 * ldw + k0;
            const int lo = lds_base + cch * 16 * 32;
            gload16(a_src + go, &Ah[lo]);
            gload16(al_src + go, &Al[lo]);
            gload16(w_src + gw, &Wh[lo]);
            gload16(wl_src + gw, &Wl[lo]);
        }
        __syncthreads();

        bf16x8 av_h[4], av_l[4], wv_h[4], wv_l[4];
        #pragma unroll
        for (int m = 0; m < 4; ++m) {
            int ar = wr + m * 16 + fr;
            av_h[m] = *(const bf16x8*)&Ah[ar * 32 + rsl];
            av_l[m] = *(const bf16x8*)&Al[ar * 32 + rsl];
        }
        #pragma unroll
        for (int n = 0; n < 4; ++n) {
            int wrw = wc + n * 16 + fr;
            wv_h[n] = *(const bf16x8*)&Wh[wrw * 32 + rsl];
            wv_l[n] = *(const bf16x8*)&Wl[wrw * 32 + rsl];
        }
        #pragma unroll
        for (int m = 0; m < 4; ++m)
            #pragma unroll
            for (int n = 0; n < 4; ++n) {
                acc[m][n] = __builtin_amdgcn_mfma_f32_16x16x32_bf16(av_h[m], wv_h[n], acc[m][n], 0, 0, 0);
                acc[m][n] = __builtin_amdgcn_mfma_f32_16x16x32_bf16(av_h[m], wv_l[n], acc[m][n], 0, 0, 0);
                acc[m][n] = __builtin_amdgcn_mfma_f32_16x16x32_bf16(av_l[m], wv_h[n], acc[m][n], 0, 0, 0);
            }
        __syncthreads();
    }

    #pragma unroll
    for (int n = 0; n < 4; ++n) {
        int col = bn + wc + n * 16 + (lane & 15);
        if (col >= Nn) continue;
        float bv = bias ? bias[col] : 0.f;
        #pragma unroll
        for (int m = 0; m < 4; ++m) {
            int row0 = bm + wr + m * 16 + (lane >> 4) * 4;
            #pragma unroll
            for (int rg = 0; rg < 4; ++rg)
                C[(size_t)(row0 + rg) * ldc + col] = acc[m][n][rg] + bv;
        }
    }
}

// =======================================================================
// small MFMA GEMM (M=128, init-only h0/c0): one wave per 16x16 tile
// =======================================================================
__global__ __launch_bounds__(256) void small_mfma_gemm(
    const float* __restrict__ A, int lda,
    const u16* __restrict__ Whi,
    const u16* __restrict__ Wlo,
    int K,
    const float* __restrict__ bias,
    float* __restrict__ C, int ldc)
{
    const int tid = threadIdx.x;
    const int wave = tid >> 6;
    const int lane = tid & 63;
    const int g = blockIdx.x * 4 + wave;
    const int mt = g & 7;
    const int nt = g >> 3;
    const int fr = lane & 15;
    const int ksl = lane >> 4;

    const float* arow = A + (size_t)(mt * 16 + fr) * lda + ksl * 8;
    const u16* bhi = Whi + (size_t)(nt * 16 + fr) * K + ksl * 8;
    const u16* blo = Wlo + (size_t)(nt * 16 + fr) * K + ksl * 8;

    f32x4 acc = {};
    for (int k0 = 0; k0 < K; k0 += 32) {
        float4 f0 = *(const float4*)(arow + k0);
        float4 f1 = *(const float4*)(arow + k0 + 4);
        U8 ah, al;
        float fv[8] = {f0.x, f0.y, f0.z, f0.w, f1.x, f1.y, f1.z, f1.w};
        #pragma unroll
        for (int j = 0; j < 8; ++j) {
            u16 hh = bf16_rne(fv[j]);
            ah.u[j] = hh;
            al.u[j] = bf16_rne(fv[j] - bf16_to_f(hh));
        }
        U8 bh, bl;
        bh.u = *(const ushortx8*)(bhi + k0);
        bl.u = *(const ushortx8*)(blo + k0);
        acc = __builtin_amdgcn_mfma_f32_16x16x32_bf16(ah.b, bh.b, acc, 0, 0, 0);
        acc = __builtin_amdgcn_mfma_f32_16x16x32_bf16(ah.b, bl.b, acc, 0, 0, 0);
        acc = __builtin_amdgcn_mfma_f32_16x16x32_bf16(al.b, bh.b, acc, 0, 0, 0);
    }

    const int n = nt * 16 + (lane & 15);
    const int m0 = mt * 16 + (lane >> 4) * 4;
    const float bv = bias ? bias[n] : 0.f;
    #pragma unroll
    for (int rg = 0; rg < 4; ++rg)
        C[(size_t)(m0 + rg) * ldc + n] = acc[rg] + bv;
}

// =======================================================================
// helpers
// =======================================================================
__global__ __launch_bounds__(256) void split_mat_kernel(
    const float* __restrict__ src, int srcld, int cols, int rows, int rows_pad,
    u16* __restrict__ hi, u16* __restrict__ lo)
{
    int idx = blockIdx.x * 256 + threadIdx.x;
    if (idx >= rows_pad * cols) return;
    int r = idx / cols, k = idx - r * cols;
    float v = (r < rows) ? src[(size_t)r * srcld + k] : 0.f;
    u16 h = bf16_rne(v);
    hi[idx] = h;
    lo[idx] = bf16_rne(v - bf16_to_f(h));
}

__global__ __launch_bounds__(256) void mean_feat_kernel(const float* __restrict__ features,
                                                        float* __restrict__ mean_f)
{
    int idx = blockIdx.x * 256 + threadIdx.x;
    int b = idx >> 11, e = idx & 2047;
    float s = 0.f;
    for (int n = 0; n < NF; ++n)
        s += features[((size_t)(b * NF + n)) * EDIM + e];
    mean_f[idx] = s * (1.0f / NF);
}

__global__ __launch_bounds__(256) void gather_embed_split_kernel(const int* __restrict__ captions,
                                                                 const float* __restrict__ embedding,
                                                                 u16* __restrict__ ehi,
                                                                 u16* __restrict__ elo)
{
    int idx = blockIdx.x * 256 + threadIdx.x;
    int m = idx >> 9;
    int j = idx & 511;
    int b = m / TT, t = m - b * TT;
    int word = captions[b * (TT + 1) + t];
    float v = embedding[(size_t)word * EMBD + j];
    u16 h = bf16_rne(v);
    ehi[idx] = h;
    elo[idx] = bf16_rne(v - bf16_to_f(h));
}

__global__ __launch_bounds__(256) void bias_sum_kernel(const float* __restrict__ b_ih,
                                                       const float* __restrict__ b_hh,
                                                       float* __restrict__ bsum)
{
    int j = blockIdx.x * 256 + threadIdx.x;
    if (j < G4) bsum[j] = b_ih[j] + b_hh[j];
}

// =======================================================================
// batch-independent persistent loop: ONE block per batch element,
// all 21 steps inside, block-local sync only (no fences, no global barrier).
// 512 threads = 8 waves. c kept in registers; h in LDS.
// =======================================================================
__global__ __launch_bounds__(512) void batch_loop_kernel(
    const float* __restrict__ h0,       // B x D
    const float* __restrict__ c0,       // B x D
    const float* __restrict__ Ua_w,     // D x D (f32, original)
    const float* __restrict__ Ua_b,     // D
    const float* __restrict__ W_hh,     // G4 x D (f32, original)
    const float* __restrict__ f_proj,   // (B*NF) x D
    const float* __restrict__ Va_w,
    const float* __restrict__ Va_b,
    const float* __restrict__ F_ih,     // (B*NF) x G4
    const float* __restrict__ E_ih,     // (B*T) x G4 (incl b_ih+b_hh)
    u16* __restrict__ H_hi, u16* __restrict__ H_lo,  // (B*T) x D
    float* __restrict__ out_w)
{
    const int b = blockIdx.x;
    const int tid = threadIdx.x;
    const int wid = tid >> 6;
    const int lane = tid & 63;
    const int grp = tid >> 3;       // 0..63 (8-thread row groups)
    const int sub = tid & 7;

    __shared__ float hl[DDIM];      // current h
    __shared__ float hpj[DDIM];     // h_proj
    __shared__ float s[64];         // softmax weights
    __shared__ float gs[G4];        // hh-matvec then full gate preacts

    float creg = c0[b * DDIM + tid];
    hl[tid] = h0[b * DDIM + tid];
    __syncthreads();

    const float* fpb = f_proj + (size_t)b * NF * DDIM;
    const float* fib = F_ih + (size_t)b * NF * G4;

    for (int t = 0; t < TT; ++t) {
        // ---- phase 1: h_proj = Ua_w @ h + Ua_b (512 rows, 8 thr/row) ----
        #pragma unroll 2
        for (int p = 0; p < 8; ++p) {
            const int row = p * 64 + grp;
            const float* wr = Ua_w + (size_t)row * DDIM + sub * 4;
            float acc = 0.f;
            #pragma unroll
            for (int kk = 0; kk < 16; ++kk) {
                float4 w4 = *(const float4*)(wr + kk * 32);
                float4 h4 = *(const float4*)(&hl[kk * 32 + sub * 4]);
                acc += w4.x * h4.x + w4.y * h4.y + w4.z * h4.z + w4.w * h4.w;
            }
            acc += __shfl_xor(acc, 1);
            acc += __shfl_xor(acc, 2);
            acc += __shfl_xor(acc, 4);
            if (sub == 0) hpj[row] = acc + Ua_b[row];
        }
        __syncthreads();

        // ---- phase 2: scores + softmax ----
        for (int n = wid; n < NF; n += 8) {
            const float* fp = fpb + (size_t)n * DDIM;
            float sum = 0.f;
            for (int d = lane; d < DDIM; d += 64)
                sum += Va_w[d] * tanhf(fp[d] + hpj[d]);
            for (int off = 32; off; off >>= 1) sum += __shfl_down(sum, off);
            if (lane == 0) s[n] = sum + Va_b[0];
        }
        __syncthreads();
        if (tid < 64) {
            float v = (lane < NF) ? s[lane] : -1e30f;
            float mx = v;
            for (int off = 32; off; off >>= 1) mx = fmaxf(mx, __shfl_xor(mx, off));
            float e = (lane < NF) ? expf(v - mx) : 0.f;
            float sm = e;
            for (int off = 32; off; off >>= 1) sm += __shfl_xor(sm, off);
            float p = e / sm;
            s[lane] = (lane < NF) ? p : 0.f;
            if (lane < NF)
                out_w[((size_t)b * TT + t) * NF + lane] = p;
        }

        // ---- phase 3: gs = W_hh @ h (2048 rows, 8 thr/row) ----
        #pragma unroll 2
        for (int p = 0; p < 32; ++p) {
            const int row = p * 64 + grp;
            const float* wr = W_hh + (size_t)row * DDIM + sub * 4;
            float acc = 0.f;
            #pragma unroll
            for (int kk = 0; kk < 16; ++kk) {
                float4 w4 = *(const float4*)(wr + kk * 32);
                float4 h4 = *(const float4*)(&hl[kk * 32 + sub * 4]);
                acc += w4.x * h4.x + w4.y * h4.y + w4.z * h4.z + w4.w * h4.w;
            }
            acc += __shfl_xor(acc, 1);
            acc += __shfl_xor(acc, 2);
            acc += __shfl_xor(acc, 4);
            if (sub == 0) gs[row] = acc;
        }
        __syncthreads();

        // ---- phase 4: gates: thread owns cols 4*tid..4*tid+3 ----
        {
            const float* eih = E_ih + ((size_t)b * TT + t) * G4 + tid * 4;
            float4 a = *(float4*)&gs[tid * 4];
            float4 e4 = *(const float4*)eih;
            a.x += e4.x; a.y += e4.y; a.z += e4.z; a.w += e4.w;
            const float* fp4 = fib + tid * 4;
            #pragma unroll 7
            for (int n = 0; n < NF; ++n) {
                float w = s[n];
                float4 f4 = *(const float4*)(fp4 + (size_t)n * G4);
                a.x += w * f4.x; a.y += w * f4.y; a.z += w * f4.z; a.w += w * f4.w;
            }
            *(float4*)&gs[tid * 4] = a;
        }
        __syncthreads();

        // ---- phase 5: LSTM (thread owns d = tid), h/c update ----
        {
            float iv = sigmoidf(gs[tid]);
            float fv = sigmoidf(gs[tid + DDIM]);
            float gv = tanhf(gs[tid + 2 * DDIM]);
            float ov = sigmoidf(gs[tid + 3 * DDIM]);
            float c2 = fv * creg + iv * gv;
            float h2 = ov * tanhf(c2);
            creg = c2;
            __syncthreads();            // all gs reads done before hl overwrite
            hl[tid] = h2;
            u16 hh = bf16_rne(h2);
            u16 hlo = bf16_rne(h2 - bf16_to_f(hh));
            size_t hix = ((size_t)b * TT + t) * DDIM + tid;
            H_hi[hix] = hh;
            H_lo[hix] = hlo;
        }
        __syncthreads();                // hl visible for next step's matvecs
    }
}

// =======================================================================
// host side
// =======================================================================
static void launch_gemm_s(hipStream_t stream,
                          const u16* Ahi, const u16* Alo, int lda,
                          const u16* Whi, const u16* Wlo, int ldw,
                          float* C, int ldc, const float* bias,
                          int M, int Nn, int K)
{
    dim3 grid((Nn + 127) / 128, M / 128);
    hipLaunchKernelGGL(gemm_bf16s, grid, dim3(256), 0, stream,
                       Ahi, Alo, lda, Whi, Wlo, ldw, C, ldc, bias, Nn, K);
}

static void launch_split(hipStream_t stream, const float* src, int srcld, int cols,
                         int rows, int rows_pad, u16* hi, u16* lo)
{
    int total = rows_pad * cols;
    hipLaunchKernelGGL(split_mat_kernel, dim3((total + 255) / 256), dim3(256), 0, stream,
                       src, srcld, cols, rows, rows_pad, hi, lo);
}

extern "C" void kernel_launch(void* const* d_in, const int* in_sizes, int n_in,
                              void* d_out, int out_size, void* d_ws, size_t ws_size,
                              hipStream_t stream)
{
    const float* features = (const float*)d_in[0];
    const int*   captions = (const int*)d_in[1];
    const float* embedding= (const float*)d_in[2];
    const float* Wa_w = (const float*)d_in[3];
    const float* Wa_b = (const float*)d_in[4];
    const float* Ua_w = (const float*)d_in[5];
    const float* Ua_b = (const float*)d_in[6];
    const float* Va_w = (const float*)d_in[7];
    const float* Va_b = (const float*)d_in[8];
    const float* W_ih = (const float*)d_in[9];
    const float* W_hh = (const float*)d_in[10];
    const float* b_ih = (const float*)d_in[11];
    const float* b_hh = (const float*)d_in[12];
    const float* ih_w = (const float*)d_in[13];
    const float* ih_b = (const float*)d_in[14];
    const float* ic_w = (const float*)d_in[15];
    const float* ic_b = (const float*)d_in[16];
    const float* fc_w = (const float*)d_in[17];
    const float* fc_b = (const float*)d_in[18];

    float* out_w = (float*)d_out;
    float* out_p = out_w + (size_t)BATCH * TT * NF;

    float* ws = (float*)d_ws;
    size_t off = 0;
    auto alloc = [&](size_t n) { float* p = ws + off; off += n; return p; };

    float* f_proj  = alloc(3211264);
    float* F_ih    = alloc(12845056);
    float* E_ih    = alloc(5505024);
    float* mean_f  = alloc(262144);
    float* h0      = alloc(65536);
    float* c0      = alloc(65536);
    float* bsum    = alloc(4096);
    u16* feat_hi = (u16*)alloc(6422528);
    u16* feat_lo = (u16*)alloc(6422528);
    u16* emb_hi  = (u16*)alloc(688128);
    u16* emb_lo  = (u16*)alloc(688128);
    u16* H_hi    = (u16*)alloc(688128);
    u16* H_lo    = (u16*)alloc(688128);
    u16* Wa_hi   = (u16*)alloc(524288);
    u16* Wa_lo   = (u16*)alloc(524288);
    u16* Wf_hi   = (u16*)alloc(2097152);
    u16* Wf_lo   = (u16*)alloc(2097152);
    u16* We_hi   = (u16*)alloc(524288);
    u16* We_lo   = (u16*)alloc(524288);
    u16* fcw_hi  = (u16*)alloc(3080192);
    u16* fcw_lo  = (u16*)alloc(3080192);

    // temp ih/ic split overlays the fc split area (stream-ordered before fc split)
    u16* T_hi = fcw_hi;
    u16* T_lo = fcw_lo;

    // ---- init ----
    hipLaunchKernelGGL(mean_feat_kernel, dim3(BATCH * EDIM / 256), dim3(256), 0, stream,
                       features, mean_f);
    launch_split(stream, ih_w, EDIM, EDIM, DDIM, DDIM, T_hi, T_lo);
    hipLaunchKernelGGL(small_mfma_gemm, dim3(DDIM / 8), dim3(256), 0, stream,
                       mean_f, EDIM, T_hi, T_lo, EDIM, ih_b, h0, DDIM);
    launch_split(stream, ic_w, EDIM, EDIM, DDIM, DDIM, T_hi, T_lo);
    hipLaunchKernelGGL(small_mfma_gemm, dim3(DDIM / 8), dim3(256), 0, stream,
                       mean_f, EDIM, T_hi, T_lo, EDIM, ic_b, c0, DDIM);
    // fc split area now free
    launch_split(stream, fc_w, DDIM, DDIM, VOC, VOCP, fcw_hi, fcw_lo);

    launch_split(stream, features, EDIM, EDIM, BATCH * NF, BATCH * NF, feat_hi, feat_lo);
    launch_split(stream, Wa_w, EDIM, EDIM, DDIM, DDIM, Wa_hi, Wa_lo);
    launch_split(stream, W_ih, EDIM + EMBD, EDIM, G4, G4, Wf_hi, Wf_lo);
    launch_split(stream, W_ih + EDIM, EDIM + EMBD, EMBD, G4, G4, We_hi, We_lo);
    hipLaunchKernelGGL(gather_embed_split_kernel, dim3(BATCH * TT * EMBD / 256), dim3(256), 0, stream,
                       captions, embedding, emb_hi, emb_lo);
    hipLaunchKernelGGL(bias_sum_kernel, dim3((G4 + 255) / 256), dim3(256), 0, stream,
                       b_ih, b_hh, bsum);

    // ---- big GEMMs (pre-split bf16x3, gload_lds) ----
    launch_gemm_s(stream, feat_hi, feat_lo, EDIM, Wa_hi, Wa_lo, EDIM,
                  f_proj, DDIM, Wa_b, BATCH * NF, DDIM, EDIM);
    launch_gemm_s(stream, feat_hi, feat_lo, EDIM, Wf_hi, Wf_lo, EDIM,
                  F_ih, G4, nullptr, BATCH * NF, G4, EDIM);
    launch_gemm_s(stream, emb_hi, emb_lo, EMBD, We_hi, We_lo, EMBD,
                  E_ih, G4, bsum, BATCH * TT, G4, EMBD);

    // ---- entire recurrence: ONE launch, block-local (per-b) only ----
    hipLaunchKernelGGL(batch_loop_kernel, dim3(BATCH), dim3(512), 0, stream,
                       h0, c0, Ua_w, Ua_b, W_hh, f_proj, Va_w, Va_b,
                       F_ih, E_ih, H_hi, H_lo, out_w);

    // ---- preds ----
    launch_gemm_s(stream, H_hi, H_lo, DDIM, fcw_hi, fcw_lo, DDIM,
                  out_p, VOC, fc_b, BATCH * TT, VOC, DDIM);
}

// Round 11
// 1605.328 us; speedup vs baseline: 3.3071x; 3.3071x over previous
//
#include <hip/hip_runtime.h>
#include <math.h>
#include <stdint.h>

#define BATCH 128
#define NF 49
#define EDIM 2048
#define EMBD 512
#define DDIM 512
#define VOC 12000
#define VOCP 12032
#define TT 21
#define G4 2048   // 4*D
#define UWN 2560  // 512 + 2048

typedef __bf16 bf16x8 __attribute__((ext_vector_type(8)));
typedef float f32x4 __attribute__((ext_vector_type(4)));
typedef unsigned short ushortx8 __attribute__((ext_vector_type(8)));
typedef unsigned short u16;

union U8 { ushortx8 u; bf16x8 b; };

__device__ __forceinline__ u16 bf16_rne(float x) {
    union { float f; unsigned u; } v; v.f = x;
    unsigned r = v.u + 0x7fffu + ((v.u >> 16) & 1u);
    return (u16)(r >> 16);
}
__device__ __forceinline__ float bf16_to_f(u16 h) {
    union { unsigned u; float f; } v; v.u = ((unsigned)h) << 16;
    return v.f;
}
__device__ __forceinline__ float sigmoidf(float x) { return 1.f / (1.f + expf(-x)); }

__device__ __forceinline__ void gload16(const void* g, void* l) {
    auto gp = reinterpret_cast<const __attribute__((address_space(1))) unsigned int*>(
        reinterpret_cast<uintptr_t>(g));
    auto lp = reinterpret_cast<__attribute__((address_space(3))) unsigned int*>(
        reinterpret_cast<uintptr_t>(l));
    __builtin_amdgcn_global_load_lds(gp, lp, 16, 0, 0);
}

// =======================================================================
// pre-split bf16x3 GEMM (proven R6): C = A*W^T (+bias), hi/lo bf16 inputs
// =======================================================================
__global__ __launch_bounds__(256) void gemm_bf16s(
    const u16* __restrict__ Ahi, const u16* __restrict__ Alo, int lda,
    const u16* __restrict__ Whi, const u16* __restrict__ Wlo, int ldw,
    float* __restrict__ C, int ldc,
    const float* __restrict__ bias,
    int Nn, int K)
{
    __shared__ u16 Ah[128 * 32];
    __shared__ u16 Al[128 * 32];
    __shared__ u16 Wh[128 * 32];
    __shared__ u16 Wl[128 * 32];

    const int nbx = gridDim.x;
    const int nwg = nbx * gridDim.y;
    const int orig = blockIdx.y * nbx + blockIdx.x;
    const int q = nwg >> 3, r = nwg & 7;
    const int xcd = orig & 7, pos = orig >> 3;
    const int swz = (xcd < r ? xcd * (q + 1) : r * (q + 1) + (xcd - r) * q) + pos;
    const int by = swz / nbx, bx = swz - by * nbx;

    const int bm = by * 128;
    const int bn = bx * 128;
    const int tid = threadIdx.x;
    const int lane = tid & 63;
    const int wid = tid >> 6;
    const int wr = (wid >> 1) * 64;
    const int wc = (wid & 1) * 64;

    const int srow = wid * 32 + (lane >> 2);
    const int sslot = (lane & 3) ^ ((lane >> 2) & 3);
    const u16* a_src = Ahi + (size_t)(bm + srow) * lda + sslot * 8;
    const u16* al_src = Alo + (size_t)(bm + srow) * lda + sslot * 8;
    const u16* w_src = Whi + (size_t)(bn + srow) * ldw + sslot * 8;
    const u16* wl_src = Wlo + (size_t)(bn + srow) * ldw + sslot * 8;
    const int lds_base = (wid * 32) * 32;

    const int fr = lane & 15;
    const int ksl = lane >> 4;
    const int rsl = (ksl ^ (fr & 3)) * 8;

    f32x4 acc[4][4] = {};

    for (int k0 = 0; k0 < K; k0 += 32) {
        #pragma unroll
        for (int cch = 0; cch < 2; ++cch) {
            const size_t go = (size_t)cch * 16 * lda + k0;
            const size_t gw = (size_t)cch * 16 * ldw + k0;
            const int lo = lds_base + cch * 16 * 32;
            gload16(a_src + go, &Ah[lo]);
            gload16(al_src + go, &Al[lo]);
            gload16(w_src + gw, &Wh[lo]);
            gload16(wl_src + gw, &Wl[lo]);
        }
        __syncthreads();

        bf16x8 av_h[4], av_l[4], wv_h[4], wv_l[4];
        #pragma unroll
        for (int m = 0; m < 4; ++m) {
            int ar = wr + m * 16 + fr;
            av_h[m] = *(const bf16x8*)&Ah[ar * 32 + rsl];
            av_l[m] = *(const bf16x8*)&Al[ar * 32 + rsl];
        }
        #pragma unroll
        for (int n = 0; n < 4; ++n) {
            int wrw = wc + n * 16 + fr;
            wv_h[n] = *(const bf16x8*)&Wh[wrw * 32 + rsl];
            wv_l[n] = *(const bf16x8*)&Wl[wrw * 32 + rsl];
        }
        #pragma unroll
        for (int m = 0; m < 4; ++m)
            #pragma unroll
            for (int n = 0; n < 4; ++n) {
                acc[m][n] = __builtin_amdgcn_mfma_f32_16x16x32_bf16(av_h[m], wv_h[n], acc[m][n], 0, 0, 0);
                acc[m][n] = __builtin_amdgcn_mfma_f32_16x16x32_bf16(av_h[m], wv_l[n], acc[m][n], 0, 0, 0);
                acc[m][n] = __builtin_amdgcn_mfma_f32_16x16x32_bf16(av_l[m], wv_h[n], acc[m][n], 0, 0, 0);
            }
        __syncthreads();
    }

    #pragma unroll
    for (int n = 0; n < 4; ++n) {
        int col = bn + wc + n * 16 + (lane & 15);
        if (col >= Nn) continue;
        float bv = bias ? bias[col] : 0.f;
        #pragma unroll
        for (int m = 0; m < 4; ++m) {
            int row0 = bm + wr + m * 16 + (lane >> 4) * 4;
            #pragma unroll
            for (int rg = 0; rg < 4; ++rg)
                C[(size_t)(row0 + rg) * ldc + col] = acc[m][n][rg] + bv;
        }
    }
}

// =======================================================================
// small MFMA GEMM (M=128): one wave per 16x16 tile
// =======================================================================
__global__ __launch_bounds__(256) void small_mfma_gemm(
    const float* __restrict__ A, int lda,
    const u16* __restrict__ Whi,
    const u16* __restrict__ Wlo,
    int K,
    const float* __restrict__ bias,
    float* __restrict__ C, int ldc)
{
    const int tid = threadIdx.x;
    const int wave = tid >> 6;
    const int lane = tid & 63;
    const int g = blockIdx.x * 4 + wave;
    const int mt = g & 7;
    const int nt = g >> 3;
    const int fr = lane & 15;
    const int ksl = lane >> 4;

    const float* arow = A + (size_t)(mt * 16 + fr) * lda + ksl * 8;
    const u16* bhi = Whi + (size_t)(nt * 16 + fr) * K + ksl * 8;
    const u16* blo = Wlo + (size_t)(nt * 16 + fr) * K + ksl * 8;

    f32x4 acc = {};
    for (int k0 = 0; k0 < K; k0 += 32) {
        float4 f0 = *(const float4*)(arow + k0);
        float4 f1 = *(const float4*)(arow + k0 + 4);
        U8 ah, al;
        float fv[8] = {f0.x, f0.y, f0.z, f0.w, f1.x, f1.y, f1.z, f1.w};
        #pragma unroll
        for (int j = 0; j < 8; ++j) {
            u16 hh = bf16_rne(fv[j]);
            ah.u[j] = hh;
            al.u[j] = bf16_rne(fv[j] - bf16_to_f(hh));
        }
        U8 bh, bl;
        bh.u = *(const ushortx8*)(bhi + k0);
        bl.u = *(const ushortx8*)(blo + k0);
        acc = __builtin_amdgcn_mfma_f32_16x16x32_bf16(ah.b, bh.b, acc, 0, 0, 0);
        acc = __builtin_amdgcn_mfma_f32_16x16x32_bf16(ah.b, bl.b, acc, 0, 0, 0);
        acc = __builtin_amdgcn_mfma_f32_16x16x32_bf16(al.b, bh.b, acc, 0, 0, 0);
    }

    const int n = nt * 16 + (lane & 15);
    const int m0 = mt * 16 + (lane >> 4) * 4;
    const float bv = bias ? bias[n] : 0.f;
    #pragma unroll
    for (int rg = 0; rg < 4; ++rg)
        C[(size_t)(m0 + rg) * ldc + n] = acc[rg] + bv;
}

// =======================================================================
// helpers
// =======================================================================
__global__ __launch_bounds__(256) void split_mat_kernel(
    const float* __restrict__ src, int srcld, int cols, int rows, int rows_pad,
    u16* __restrict__ hi, u16* __restrict__ lo)
{
    int idx = blockIdx.x * 256 + threadIdx.x;
    if (idx >= rows_pad * cols) return;
    int r = idx / cols, k = idx - r * cols;
    float v = (r < rows) ? src[(size_t)r * srcld + k] : 0.f;
    u16 h = bf16_rne(v);
    hi[idx] = h;
    lo[idx] = bf16_rne(v - bf16_to_f(h));
}

__global__ __launch_bounds__(256) void uw_split_kernel(const float* __restrict__ Ua_w,
                                                       const float* __restrict__ Ua_b,
                                                       const float* __restrict__ W_hh,
                                                       u16* __restrict__ hi,
                                                       u16* __restrict__ lo,
                                                       float* __restrict__ biascat)
{
    int idx = blockIdx.x * 256 + threadIdx.x;
    if (idx < UWN * DDIM) {
        int n = idx >> 9, k = idx & 511;
        float v = (n < DDIM) ? Ua_w[n * DDIM + k] : W_hh[(size_t)(n - DDIM) * DDIM + k];
        u16 h = bf16_rne(v);
        hi[idx] = h;
        lo[idx] = bf16_rne(v - bf16_to_f(h));
    }
    if (idx < UWN)
        biascat[idx] = (idx < DDIM) ? Ua_b[idx] : 0.f;
}

__global__ __launch_bounds__(256) void mean_feat_kernel(const float* __restrict__ features,
                                                        float* __restrict__ mean_f)
{
    int idx = blockIdx.x * 256 + threadIdx.x;
    int b = idx >> 11, e = idx & 2047;
    float s = 0.f;
    for (int n = 0; n < NF; ++n)
        s += features[((size_t)(b * NF + n)) * EDIM + e];
    mean_f[idx] = s * (1.0f / NF);
}

__global__ __launch_bounds__(256) void gather_embed_split_kernel(const int* __restrict__ captions,
                                                                 const float* __restrict__ embedding,
                                                                 u16* __restrict__ ehi,
                                                                 u16* __restrict__ elo)
{
    int idx = blockIdx.x * 256 + threadIdx.x;
    int m = idx >> 9;
    int j = idx & 511;
    int b = m / TT, t = m - b * TT;
    int word = captions[b * (TT + 1) + t];
    float v = embedding[(size_t)word * EMBD + j];
    u16 h = bf16_rne(v);
    ehi[idx] = h;
    elo[idx] = bf16_rne(v - bf16_to_f(h));
}

__global__ __launch_bounds__(256) void bias_sum_kernel(const float* __restrict__ b_ih,
                                                       const float* __restrict__ b_hh,
                                                       float* __restrict__ bsum)
{
    int j = blockIdx.x * 256 + threadIdx.x;
    if (j < G4) bsum[j] = b_ih[j] + b_hh[j];
}

// =======================================================================
// fused per-step v3: 256 blocks x 512 threads (2 blocks/CU, 16 waves/CU).
// block = (b, dh). Gates phase: 256 column-group threads x 2 n-halves.
// =======================================================================
__global__ __launch_bounds__(512) void fused_step3_kernel(
    const float* __restrict__ f_proj,   // (B*NF) x 512
    const float* __restrict__ hp_g,     // B x 2560: [h_proj | hh-gates]
    const float* __restrict__ Va_w,
    const float* __restrict__ Va_b,
    const float* __restrict__ F_ih,     // (B*NF) x 2048
    const float* __restrict__ E_ih,     // (B*T) x 2048 (incl b_ih+b_hh)
    float* __restrict__ h,              // B x D (f32, for next hp GEMM)
    float* __restrict__ c,              // B x D
    u16* __restrict__ H_hi, u16* __restrict__ H_lo,  // (B*T) x D
    float* __restrict__ out_w,
    int t)
{
    const int b  = blockIdx.x >> 1;
    const int dh = blockIdx.x & 1;
    const int tid = threadIdx.x;
    const int wid = tid >> 6;
    const int lane = tid & 63;
    __shared__ float s[64];
    __shared__ float pb[1024];          // partial sums from n-half 1
    __shared__ float gs2[1024];         // final gate preacts (cg-major x4)

    // ---- scores + softmax (redundant per d-half) ----
    const float* hp = hp_g + (size_t)b * UWN;
    for (int n = wid; n < NF; n += 8) {
        const float* fp = f_proj + ((size_t)(b * NF + n)) * DDIM;
        float sum = 0.f;
        for (int d = lane; d < DDIM; d += 64)
            sum += Va_w[d] * tanhf(fp[d] + hp[d]);
        for (int off = 32; off; off >>= 1) sum += __shfl_down(sum, off);
        if (lane == 0) s[n] = sum + Va_b[0];
    }
    __syncthreads();
    if (tid < 64) {
        float v = (lane < NF) ? s[lane] : -1e30f;
        float mx = v;
        for (int off = 32; off; off >>= 1) mx = fmaxf(mx, __shfl_xor(mx, off));
        float e = (lane < NF) ? expf(v - mx) : 0.f;
        float sm = e;
        for (int off = 32; off; off >>= 1) sm += __shfl_xor(sm, off);
        float p = e / sm;
        s[lane] = (lane < NF) ? p : 0.f;
        if (dh == 0 && lane < NF)
            out_w[((size_t)b * TT + t) * NF + lane] = p;
    }
    __syncthreads();

    // ---- gates: cg = col-group of 4 cols; nh = n-half ----
    const int cg = tid & 255;               // 0..255
    const int nh = tid >> 8;                // 0 or 1
    const int q  = cg >> 6;                 // gate 0..3
    const int dl = (cg & 63) * 4;           // local d in half (0..252)
    const int gcol = q * DDIM + dh * 256 + dl;
    const float* fib = F_ih + (size_t)b * NF * G4 + gcol;

    float4 a;
    if (nh == 0) {
        a = *(const float4*)(hp + DDIM + gcol);
        float4 e4 = *(const float4*)(E_ih + ((size_t)b * TT + t) * G4 + gcol);
        a.x += e4.x; a.y += e4.y; a.z += e4.z; a.w += e4.w;
    } else {
        a = make_float4(0.f, 0.f, 0.f, 0.f);
    }
    const int n0 = nh ? 25 : 0;
    const int n1 = nh ? NF : 25;
    #pragma unroll 5
    for (int n = n0; n < n1; ++n) {
        float w = s[n];
        float4 f4 = *(const float4*)(fib + (size_t)n * G4);
        a.x += w * f4.x; a.y += w * f4.y; a.z += w * f4.z; a.w += w * f4.w;
    }
    if (nh == 1) *(float4*)&pb[cg * 4] = a;
    __syncthreads();
    if (nh == 0) {
        float4 p4 = *(const float4*)&pb[cg * 4];
        a.x += p4.x; a.y += p4.y; a.z += p4.z; a.w += p4.w;
        *(float4*)&gs2[cg * 4] = a;
    }
    __syncthreads();

    // ---- LSTM: 64 threads x 4 d ----
    if (tid < 64) {
        const int d   = dh * 256 + tid * 4;
        const int idx = b * DDIM + d;
        float4 iv4 = *(const float4*)&gs2[(0 * 64 + tid) * 4];
        float4 fv4 = *(const float4*)&gs2[(1 * 64 + tid) * 4];
        float4 gv4 = *(const float4*)&gs2[(2 * 64 + tid) * 4];
        float4 ov4 = *(const float4*)&gs2[(3 * 64 + tid) * 4];
        float4 cold = *(const float4*)(c + idx);
        float ci[4] = {cold.x, cold.y, cold.z, cold.w};
        float ii[4] = {iv4.x, iv4.y, iv4.z, iv4.w};
        float ff[4] = {fv4.x, fv4.y, fv4.z, fv4.w};
        float gg[4] = {gv4.x, gv4.y, gv4.z, gv4.w};
        float oo[4] = {ov4.x, ov4.y, ov4.z, ov4.w};
        float co[4], ho[4];
        u16 hh4[4], hl4[4];
        #pragma unroll
        for (int k = 0; k < 4; ++k) {
            float iv = sigmoidf(ii[k]);
            float fv = sigmoidf(ff[k]);
            float gv = tanhf(gg[k]);
            float ov = sigmoidf(oo[k]);
            float c2 = fv * ci[k] + iv * gv;
            float h2 = ov * tanhf(c2);
            co[k] = c2; ho[k] = h2;
            hh4[k] = bf16_rne(h2);
            hl4[k] = bf16_rne(h2 - bf16_to_f(hh4[k]));
        }
        *(float4*)(c + idx) = make_float4(co[0], co[1], co[2], co[3]);
        *(float4*)(h + idx) = make_float4(ho[0], ho[1], ho[2], ho[3]);
        size_t hix = ((size_t)b * TT + t) * DDIM + d;
        *(ushort4*)(H_hi + hix) = make_ushort4(hh4[0], hh4[1], hh4[2], hh4[3]);
        *(ushort4*)(H_lo + hix) = make_ushort4(hl4[0], hl4[1], hl4[2], hl4[3]);
    }
}

// =======================================================================
// host side
// =======================================================================
static void launch_gemm_s(hipStream_t stream,
                          const u16* Ahi, const u16* Alo, int lda,
                          const u16* Whi, const u16* Wlo, int ldw,
                          float* C, int ldc, const float* bias,
                          int M, int Nn, int K)
{
    dim3 grid((Nn + 127) / 128, M / 128);
    hipLaunchKernelGGL(gemm_bf16s, grid, dim3(256), 0, stream,
                       Ahi, Alo, lda, Whi, Wlo, ldw, C, ldc, bias, Nn, K);
}

static void launch_split(hipStream_t stream, const float* src, int srcld, int cols,
                         int rows, int rows_pad, u16* hi, u16* lo)
{
    int total = rows_pad * cols;
    hipLaunchKernelGGL(split_mat_kernel, dim3((total + 255) / 256), dim3(256), 0, stream,
                       src, srcld, cols, rows, rows_pad, hi, lo);
}

extern "C" void kernel_launch(void* const* d_in, const int* in_sizes, int n_in,
                              void* d_out, int out_size, void* d_ws, size_t ws_size,
                              hipStream_t stream)
{
    const float* features = (const float*)d_in[0];
    const int*   captions = (const int*)d_in[1];
    const float* embedding= (const float*)d_in[2];
    const float* Wa_w = (const float*)d_in[3];
    const float* Wa_b = (const float*)d_in[4];
    const float* Ua_w = (const float*)d_in[5];
    const float* Ua_b = (const float*)d_in[6];
    const float* Va_w = (const float*)d_in[7];
    const float* Va_b = (const float*)d_in[8];
    const float* W_ih = (const float*)d_in[9];
    const float* W_hh = (const float*)d_in[10];
    const float* b_ih = (const float*)d_in[11];
    const float* b_hh = (const float*)d_in[12];
    const float* ih_w = (const float*)d_in[13];
    const float* ih_b = (const float*)d_in[14];
    const float* ic_w = (const float*)d_in[15];
    const float* ic_b = (const float*)d_in[16];
    const float* fc_w = (const float*)d_in[17];
    const float* fc_b = (const float*)d_in[18];

    float* out_w = (float*)d_out;
    float* out_p = out_w + (size_t)BATCH * TT * NF;

    float* ws = (float*)d_ws;
    size_t off = 0;
    auto alloc = [&](size_t n) { float* p = ws + off; off += n; return p; };

    float* f_proj  = alloc(3211264);
    float* F_ih    = alloc(12845056);
    float* E_ih    = alloc(5505024);
    float* hp_g    = alloc(327680);
    float* mean_f  = alloc(262144);
    float* h       = alloc(65536);
    float* c       = alloc(65536);
    float* bsum    = alloc(4096);
    float* biascat = alloc(4096);
    u16* feat_hi = (u16*)alloc(6422528);
    u16* feat_lo = (u16*)alloc(6422528);
    u16* emb_hi  = (u16*)alloc(688128);
    u16* emb_lo  = (u16*)alloc(688128);
    u16* H_hi    = (u16*)alloc(688128);
    u16* H_lo    = (u16*)alloc(688128);
    u16* Wa_hi   = (u16*)alloc(524288);
    u16* Wa_lo   = (u16*)alloc(524288);
    u16* Wf_hi   = (u16*)alloc(2097152);
    u16* Wf_lo   = (u16*)alloc(2097152);
    u16* We_hi   = (u16*)alloc(524288);
    u16* We_lo   = (u16*)alloc(524288);
    u16* UW_hi   = (u16*)alloc(655360);
    u16* UW_lo   = (u16*)alloc(655360);
    u16* fcw_hi  = (u16*)alloc(3080192);
    u16* fcw_lo  = (u16*)alloc(3080192);

    // temp ih/ic split overlays the fc split area (stream-ordered before fc split)
    u16* T_hi = fcw_hi;
    u16* T_lo = fcw_lo;

    // ---- init ----
    hipLaunchKernelGGL(mean_feat_kernel, dim3(BATCH * EDIM / 256), dim3(256), 0, stream,
                       features, mean_f);
    launch_split(stream, ih_w, EDIM, EDIM, DDIM, DDIM, T_hi, T_lo);
    hipLaunchKernelGGL(small_mfma_gemm, dim3(DDIM / 8), dim3(256), 0, stream,
                       mean_f, EDIM, T_hi, T_lo, EDIM, ih_b, h, DDIM);
    launch_split(stream, ic_w, EDIM, EDIM, DDIM, DDIM, T_hi, T_lo);
    hipLaunchKernelGGL(small_mfma_gemm, dim3(DDIM / 8), dim3(256), 0, stream,
                       mean_f, EDIM, T_hi, T_lo, EDIM, ic_b, c, DDIM);
    // fc split area now free
    launch_split(stream, fc_w, DDIM, DDIM, VOC, VOCP, fcw_hi, fcw_lo);

    launch_split(stream, features, EDIM, EDIM, BATCH * NF, BATCH * NF, feat_hi, feat_lo);
    launch_split(stream, Wa_w, EDIM, EDIM, DDIM, DDIM, Wa_hi, Wa_lo);
    launch_split(stream, W_ih, EDIM + EMBD, EDIM, G4, G4, Wf_hi, Wf_lo);
    launch_split(stream, W_ih + EDIM, EDIM + EMBD, EMBD, G4, G4, We_hi, We_lo);
    hipLaunchKernelGGL(gather_embed_split_kernel, dim3(BATCH * TT * EMBD / 256), dim3(256), 0, stream,
                       captions, embedding, emb_hi, emb_lo);
    hipLaunchKernelGGL(bias_sum_kernel, dim3((G4 + 255) / 256), dim3(256), 0, stream,
                       b_ih, b_hh, bsum);
    hipLaunchKernelGGL(uw_split_kernel, dim3((UWN * DDIM + 255) / 256), dim3(256), 0, stream,
                       Ua_w, Ua_b, W_hh, UW_hi, UW_lo, biascat);

    // ---- big GEMMs (pre-split bf16x3, gload_lds) ----
    launch_gemm_s(stream, feat_hi, feat_lo, EDIM, Wa_hi, Wa_lo, EDIM,
                  f_proj, DDIM, Wa_b, BATCH * NF, DDIM, EDIM);
    launch_gemm_s(stream, feat_hi, feat_lo, EDIM, Wf_hi, Wf_lo, EDIM,
                  F_ih, G4, nullptr, BATCH * NF, G4, EDIM);
    launch_gemm_s(stream, emb_hi, emb_lo, EMBD, We_hi, We_lo, EMBD,
                  E_ih, G4, bsum, BATCH * TT, G4, EMBD);

    // ---- sequential loop: 2 launches/step ----
    for (int t = 0; t < TT; ++t) {
        hipLaunchKernelGGL(small_mfma_gemm, dim3(UWN / 8), dim3(256), 0, stream,
                           h, DDIM, UW_hi, UW_lo, DDIM, biascat, hp_g, UWN);
        hipLaunchKernelGGL(fused_step3_kernel, dim3(BATCH * 2), dim3(512), 0, stream,
                           f_proj, hp_g, Va_w, Va_b, F_ih, E_ih, h, c,
                           H_hi, H_lo, out_w, t);
    }

    // ---- preds ----
    launch_gemm_s(stream, H_hi, H_lo, DDIM, fcw_hi, fcw_lo, DDIM,
                  out_p, VOC, fc_b, BATCH * TT, VOC, DDIM);
}

// Round 12
// 1498.712 us; speedup vs baseline: 3.5423x; 1.0711x over previous
//
#include <hip/hip_runtime.h>
#include <math.h>
#include <stdint.h>

#define BATCH 128
#define NF 49
#define EDIM 2048
#define EMBD 512
#define DDIM 512
#define VOC 12000
#define VOCP 12032
#define TT 21
#define G4 2048   // 4*D
#define UWN 2560  // 512 + 2048

typedef __bf16 bf16x8 __attribute__((ext_vector_type(8)));
typedef float f32x4 __attribute__((ext_vector_type(4)));
typedef unsigned short ushortx8 __attribute__((ext_vector_type(8)));
typedef unsigned short u16;

union U8 { ushortx8 u; bf16x8 b; };

__device__ __forceinline__ u16 bf16_rne(float x) {
    union { float f; unsigned u; } v; v.f = x;
    unsigned r = v.u + 0x7fffu + ((v.u >> 16) & 1u);
    return (u16)(r >> 16);
}
__device__ __forceinline__ float bf16_to_f(u16 h) {
    union { unsigned u; float f; } v; v.u = ((unsigned)h) << 16;
    return v.f;
}
__device__ __forceinline__ float sigmoidf(float x) { return 1.f / (1.f + expf(-x)); }

__device__ __forceinline__ void gload16(const void* g, void* l) {
    auto gp = reinterpret_cast<const __attribute__((address_space(1))) unsigned int*>(
        reinterpret_cast<uintptr_t>(g));
    auto lp = reinterpret_cast<__attribute__((address_space(3))) unsigned int*>(
        reinterpret_cast<uintptr_t>(l));
    __builtin_amdgcn_global_load_lds(gp, lp, 16, 0, 0);
}

// =======================================================================
// pre-split bf16x3 GEMM (proven R6 structure) with TWO-DEST epilogue:
// cols < nsplit -> C1, else C2 (col-nsplit). bias indexed by global col.
// =======================================================================
__global__ __launch_bounds__(256) void gemm_bf16s2(
    const u16* __restrict__ Ahi, const u16* __restrict__ Alo, int lda,
    const u16* __restrict__ Whi, const u16* __restrict__ Wlo, int ldw,
    float* __restrict__ C1, int ldc1,
    float* __restrict__ C2, int ldc2, int nsplit,
    const float* __restrict__ bias,
    int Nn, int K)
{
    __shared__ u16 Ah[128 * 32];
    __shared__ u16 Al[128 * 32];
    __shared__ u16 Wh[128 * 32];
    __shared__ u16 Wl[128 * 32];

    const int nbx = gridDim.x;
    const int nwg = nbx * gridDim.y;
    const int orig = blockIdx.y * nbx + blockIdx.x;
    const int q = nwg >> 3, r = nwg & 7;
    const int xcd = orig & 7, pos = orig >> 3;
    const int swz = (xcd < r ? xcd * (q + 1) : r * (q + 1) + (xcd - r) * q) + pos;
    const int by = swz / nbx, bx = swz - by * nbx;

    const int bm = by * 128;
    const int bn = bx * 128;
    const int tid = threadIdx.x;
    const int lane = tid & 63;
    const int wid = tid >> 6;
    const int wr = (wid >> 1) * 64;
    const int wc = (wid & 1) * 64;

    const int srow = wid * 32 + (lane >> 2);
    const int sslot = (lane & 3) ^ ((lane >> 2) & 3);
    const u16* a_src = Ahi + (size_t)(bm + srow) * lda + sslot * 8;
    const u16* al_src = Alo + (size_t)(bm + srow) * lda + sslot * 8;
    const u16* w_src = Whi + (size_t)(bn + srow) * ldw + sslot * 8;
    const u16* wl_src = Wlo + (size_t)(bn + srow) * ldw + sslot * 8;
    const int lds_base = (wid * 32) * 32;

    const int fr = lane & 15;
    const int ksl = lane >> 4;
    const int rsl = (ksl ^ (fr & 3)) * 8;

    f32x4 acc[4][4] = {};

    for (int k0 = 0; k0 < K; k0 += 32) {
        #pragma unroll
        for (int cch = 0; cch < 2; ++cch) {
            const size_t go = (size_t)cch * 16 * lda + k0;
            const size_t gw = (size_t)cch * 16 * ldw + k0;
            const int lo = lds_base + cch * 16 * 32;
            gload16(a_src + go, &Ah[lo]);
            gload16(al_src + go, &Al[lo]);
            gload16(w_src + gw, &Wh[lo]);
            gload16(wl_src + gw, &Wl[lo]);
        }
        __syncthreads();

        bf16x8 av_h[4], av_l[4], wv_h[4], wv_l[4];
        #pragma unroll
        for (int m = 0; m < 4; ++m) {
            int ar = wr + m * 16 + fr;
            av_h[m] = *(const bf16x8*)&Ah[ar * 32 + rsl];
            av_l[m] = *(const bf16x8*)&Al[ar * 32 + rsl];
        }
        #pragma unroll
        for (int n = 0; n < 4; ++n) {
            int wrw = wc + n * 16 + fr;
            wv_h[n] = *(const bf16x8*)&Wh[wrw * 32 + rsl];
            wv_l[n] = *(const bf16x8*)&Wl[wrw * 32 + rsl];
        }
        #pragma unroll
        for (int m = 0; m < 4; ++m)
            #pragma unroll
            for (int n = 0; n < 4; ++n) {
                acc[m][n] = __builtin_amdgcn_mfma_f32_16x16x32_bf16(av_h[m], wv_h[n], acc[m][n], 0, 0, 0);
                acc[m][n] = __builtin_amdgcn_mfma_f32_16x16x32_bf16(av_h[m], wv_l[n], acc[m][n], 0, 0, 0);
                acc[m][n] = __builtin_amdgcn_mfma_f32_16x16x32_bf16(av_l[m], wv_h[n], acc[m][n], 0, 0, 0);
            }
        __syncthreads();
    }

    #pragma unroll
    for (int n = 0; n < 4; ++n) {
        int col = bn + wc + n * 16 + (lane & 15);
        if (col >= Nn) continue;
        float bv = bias ? bias[col] : 0.f;
        float* Cd; int ldcd; int cc;
        if (col < nsplit) { Cd = C1; ldcd = ldc1; cc = col; }
        else              { Cd = C2; ldcd = ldc2; cc = col - nsplit; }
        #pragma unroll
        for (int m = 0; m < 4; ++m) {
            int row0 = bm + wr + m * 16 + (lane >> 4) * 4;
            #pragma unroll
            for (int rg = 0; rg < 4; ++rg)
                Cd[(size_t)(row0 + rg) * ldcd + cc] = acc[m][n][rg] + bv;
        }
    }
}

// =======================================================================
// small MFMA GEMM (M=128) with two-dest epilogue: one wave per 16x16 tile
// =======================================================================
__global__ __launch_bounds__(256) void small_mfma_gemm2(
    const float* __restrict__ A, int lda,
    const u16* __restrict__ Whi,
    const u16* __restrict__ Wlo,
    int K,
    const float* __restrict__ bias,
    float* __restrict__ C1, int ldc1,
    float* __restrict__ C2, int ldc2, int nsplit)
{
    const int tid = threadIdx.x;
    const int wave = tid >> 6;
    const int lane = tid & 63;
    const int g = blockIdx.x * 4 + wave;
    const int mt = g & 7;
    const int nt = g >> 3;
    const int fr = lane & 15;
    const int ksl = lane >> 4;

    const float* arow = A + (size_t)(mt * 16 + fr) * lda + ksl * 8;
    const u16* bhi = Whi + (size_t)(nt * 16 + fr) * K + ksl * 8;
    const u16* blo = Wlo + (size_t)(nt * 16 + fr) * K + ksl * 8;

    f32x4 acc = {};
    for (int k0 = 0; k0 < K; k0 += 32) {
        float4 f0 = *(const float4*)(arow + k0);
        float4 f1 = *(const float4*)(arow + k0 + 4);
        U8 ah, al;
        float fv[8] = {f0.x, f0.y, f0.z, f0.w, f1.x, f1.y, f1.z, f1.w};
        #pragma unroll
        for (int j = 0; j < 8; ++j) {
            u16 hh = bf16_rne(fv[j]);
            ah.u[j] = hh;
            al.u[j] = bf16_rne(fv[j] - bf16_to_f(hh));
        }
        U8 bh, bl;
        bh.u = *(const ushortx8*)(bhi + k0);
        bl.u = *(const ushortx8*)(blo + k0);
        acc = __builtin_amdgcn_mfma_f32_16x16x32_bf16(ah.b, bh.b, acc, 0, 0, 0);
        acc = __builtin_amdgcn_mfma_f32_16x16x32_bf16(ah.b, bl.b, acc, 0, 0, 0);
        acc = __builtin_amdgcn_mfma_f32_16x16x32_bf16(al.b, bh.b, acc, 0, 0, 0);
    }

    const int n = nt * 16 + (lane & 15);
    const int m0 = mt * 16 + (lane >> 4) * 4;
    const float bv = bias ? bias[n] : 0.f;
    float* Cd; int ldcd; int cc;
    if (n < nsplit) { Cd = C1; ldcd = ldc1; cc = n; }
    else            { Cd = C2; ldcd = ldc2; cc = n - nsplit; }
    #pragma unroll
    for (int rg = 0; rg < 4; ++rg)
        Cd[(size_t)(m0 + rg) * ldcd + cc] = acc[rg] + bv;
}

// =======================================================================
// mega split: ALL weight hi/lo splits + bias builds in ONE launch.
// segment layout (element idx spaces, sizes in elements):
//  S0 [0, 2097152)        ihic  (1024 x 2048)  -> T (fcw overlay)
//  S1 [.., 7340032)       WaWf  (2560 x 2048)  -> WaWf
//  S2 [.., 8388608)       We    (2048 x 512)   -> We
//  S3 [.., 9699328)       UW    (2560 x 512)   -> UW
//  S4 [.., 22544384)      features (6272x2048) -> feat
//  S5 [.., 22552576)      biases (f32 direct)
// =======================================================================
#define MS_C0 2097152
#define MS_C1 7340032
#define MS_C2 8388608
#define MS_C3 9699328
#define MS_C4 22544384
#define MS_C5 22552576

__global__ __launch_bounds__(256) void mega_split_kernel(
    const float* __restrict__ ih_w, const float* __restrict__ ic_w,
    const float* __restrict__ Wa_w, const float* __restrict__ W_ih,
    const float* __restrict__ Ua_w, const float* __restrict__ W_hh,
    const float* __restrict__ features,
    const float* __restrict__ b_ih, const float* __restrict__ b_hh,
    const float* __restrict__ Ua_b, const float* __restrict__ Wa_b,
    const float* __restrict__ ih_b, const float* __restrict__ ic_b,
    u16* __restrict__ T_hi, u16* __restrict__ T_lo,
    u16* __restrict__ WaWf_hi, u16* __restrict__ WaWf_lo,
    u16* __restrict__ We_hi, u16* __restrict__ We_lo,
    u16* __restrict__ UW_hi, u16* __restrict__ UW_lo,
    u16* __restrict__ feat_hi, u16* __restrict__ feat_lo,
    float* __restrict__ bsum, float* __restrict__ biascat,
    float* __restrict__ bias_fp, float* __restrict__ bias_hc)
{
    const int idx = blockIdx.x * 256 + threadIdx.x;
    float v; u16* hi; u16* lo; int j;

    if (idx < MS_C0) {
        j = idx; int r = j >> 11, k = j & 2047;
        v = (r < 512) ? ih_w[(size_t)r * 2048 + k] : ic_w[(size_t)(r - 512) * 2048 + k];
        hi = T_hi; lo = T_lo;
    } else if (idx < MS_C1) {
        j = idx - MS_C0; int r = j >> 11, k = j & 2047;
        v = (r < 512) ? Wa_w[(size_t)r * 2048 + k] : W_ih[(size_t)(r - 512) * 2560 + k];
        hi = WaWf_hi; lo = WaWf_lo;
    } else if (idx < MS_C2) {
        j = idx - MS_C1; int r = j >> 9, k = j & 511;
        v = W_ih[(size_t)r * 2560 + 2048 + k];
        hi = We_hi; lo = We_lo;
    } else if (idx < MS_C3) {
        j = idx - MS_C2; int r = j >> 9, k = j & 511;
        v = (r < 512) ? Ua_w[(size_t)r * 512 + k] : W_hh[(size_t)(r - 512) * 512 + k];
        hi = UW_hi; lo = UW_lo;
    } else if (idx < MS_C4) {
        j = idx - MS_C3;
        v = features[j];
        hi = feat_hi; lo = feat_lo;
    } else {
        j = idx - MS_C4;
        if (j < 2048)       bsum[j] = b_ih[j] + b_hh[j];
        else if (j < 4608)  { int jj = j - 2048; biascat[jj] = (jj < 512) ? Ua_b[jj] : 0.f; }
        else if (j < 7168)  { int jj = j - 4608; bias_fp[jj] = (jj < 512) ? Wa_b[jj] : 0.f; }
        else                { int jj = j - 7168; bias_hc[jj] = (jj < 512) ? ih_b[jj] : ic_b[jj - 512]; }
        return;
    }
    u16 h = bf16_rne(v);
    hi[j] = h;
    lo[j] = bf16_rne(v - bf16_to_f(h));
}

// fc split (runs after h0c0 GEMM frees the T overlay)
__global__ __launch_bounds__(256) void split_mat_kernel(
    const float* __restrict__ src, int srcld, int cols, int rows, int rows_pad,
    u16* __restrict__ hi, u16* __restrict__ lo)
{
    int idx = blockIdx.x * 256 + threadIdx.x;
    if (idx >= rows_pad * cols) return;
    int r = idx / cols, k = idx - r * cols;
    float v = (r < rows) ? src[(size_t)r * srcld + k] : 0.f;
    u16 h = bf16_rne(v);
    hi[idx] = h;
    lo[idx] = bf16_rne(v - bf16_to_f(h));
}

__global__ __launch_bounds__(256) void mean_feat_kernel(const float* __restrict__ features,
                                                        float* __restrict__ mean_f)
{
    int idx = blockIdx.x * 256 + threadIdx.x;
    int b = idx >> 11, e = idx & 2047;
    float s = 0.f;
    for (int n = 0; n < NF; ++n)
        s += features[((size_t)(b * NF + n)) * EDIM + e];
    mean_f[idx] = s * (1.0f / NF);
}

__global__ __launch_bounds__(256) void gather_embed_split_kernel(const int* __restrict__ captions,
                                                                 const float* __restrict__ embedding,
                                                                 u16* __restrict__ ehi,
                                                                 u16* __restrict__ elo)
{
    int idx = blockIdx.x * 256 + threadIdx.x;
    int m = idx >> 9;
    int j = idx & 511;
    int b = m / TT, t = m - b * TT;
    int word = captions[b * (TT + 1) + t];
    float v = embedding[(size_t)word * EMBD + j];
    u16 h = bf16_rne(v);
    ehi[idx] = h;
    elo[idx] = bf16_rne(v - bf16_to_f(h));
}

// =======================================================================
// fused per-step v3 (proven R11): 256 blocks x 512 threads
// =======================================================================
__global__ __launch_bounds__(512) void fused_step3_kernel(
    const float* __restrict__ f_proj,
    const float* __restrict__ hp_g,
    const float* __restrict__ Va_w,
    const float* __restrict__ Va_b,
    const float* __restrict__ F_ih,
    const float* __restrict__ E_ih,
    float* __restrict__ h,
    float* __restrict__ c,
    u16* __restrict__ H_hi, u16* __restrict__ H_lo,
    float* __restrict__ out_w,
    int t)
{
    const int b  = blockIdx.x >> 1;
    const int dh = blockIdx.x & 1;
    const int tid = threadIdx.x;
    const int wid = tid >> 6;
    const int lane = tid & 63;
    __shared__ float s[64];
    __shared__ float pb[1024];
    __shared__ float gs2[1024];

    const float* hp = hp_g + (size_t)b * UWN;
    for (int n = wid; n < NF; n += 8) {
        const float* fp = f_proj + ((size_t)(b * NF + n)) * DDIM;
        float sum = 0.f;
        for (int d = lane; d < DDIM; d += 64)
            sum += Va_w[d] * tanhf(fp[d] + hp[d]);
        for (int off = 32; off; off >>= 1) sum += __shfl_down(sum, off);
        if (lane == 0) s[n] = sum + Va_b[0];
    }
    __syncthreads();
    if (tid < 64) {
        float v = (lane < NF) ? s[lane] : -1e30f;
        float mx = v;
        for (int off = 32; off; off >>= 1) mx = fmaxf(mx, __shfl_xor(mx, off));
        float e = (lane < NF) ? expf(v - mx) : 0.f;
        float sm = e;
        for (int off = 32; off; off >>= 1) sm += __shfl_xor(sm, off);
        float p = e / sm;
        s[lane] = (lane < NF) ? p : 0.f;
        if (dh == 0 && lane < NF)
            out_w[((size_t)b * TT + t) * NF + lane] = p;
    }
    __syncthreads();

    const int cg = tid & 255;
    const int nh = tid >> 8;
    const int q  = cg >> 6;
    const int dl = (cg & 63) * 4;
    const int gcol = q * DDIM + dh * 256 + dl;
    const float* fib = F_ih + (size_t)b * NF * G4 + gcol;

    float4 a;
    if (nh == 0) {
        a = *(const float4*)(hp + DDIM + gcol);
        float4 e4 = *(const float4*)(E_ih + ((size_t)b * TT + t) * G4 + gcol);
        a.x += e4.x; a.y += e4.y; a.z += e4.z; a.w += e4.w;
    } else {
        a = make_float4(0.f, 0.f, 0.f, 0.f);
    }
    const int n0 = nh ? 25 : 0;
    const int n1 = nh ? NF : 25;
    #pragma unroll 5
    for (int n = n0; n < n1; ++n) {
        float w = s[n];
        float4 f4 = *(const float4*)(fib + (size_t)n * G4);
        a.x += w * f4.x; a.y += w * f4.y; a.z += w * f4.z; a.w += w * f4.w;
    }
    if (nh == 1) *(float4*)&pb[cg * 4] = a;
    __syncthreads();
    if (nh == 0) {
        float4 p4 = *(const float4*)&pb[cg * 4];
        a.x += p4.x; a.y += p4.y; a.z += p4.z; a.w += p4.w;
        *(float4*)&gs2[cg * 4] = a;
    }
    __syncthreads();

    if (tid < 64) {
        const int d   = dh * 256 + tid * 4;
        const int idx = b * DDIM + d;
        float4 iv4 = *(const float4*)&gs2[(0 * 64 + tid) * 4];
        float4 fv4 = *(const float4*)&gs2[(1 * 64 + tid) * 4];
        float4 gv4 = *(const float4*)&gs2[(2 * 64 + tid) * 4];
        float4 ov4 = *(const float4*)&gs2[(3 * 64 + tid) * 4];
        float4 cold = *(const float4*)(c + idx);
        float ci[4] = {cold.x, cold.y, cold.z, cold.w};
        float ii[4] = {iv4.x, iv4.y, iv4.z, iv4.w};
        float ff[4] = {fv4.x, fv4.y, fv4.z, fv4.w};
        float gg[4] = {gv4.x, gv4.y, gv4.z, gv4.w};
        float oo[4] = {ov4.x, ov4.y, ov4.z, ov4.w};
        float co[4], ho[4];
        u16 hh4[4], hl4[4];
        #pragma unroll
        for (int k = 0; k < 4; ++k) {
            float iv = sigmoidf(ii[k]);
            float fv = sigmoidf(ff[k]);
            float gv = tanhf(gg[k]);
            float ov = sigmoidf(oo[k]);
            float c2 = fv * ci[k] + iv * gv;
            float h2 = ov * tanhf(c2);
            co[k] = c2; ho[k] = h2;
            hh4[k] = bf16_rne(h2);
            hl4[k] = bf16_rne(h2 - bf16_to_f(hh4[k]));
        }
        *(float4*)(c + idx) = make_float4(co[0], co[1], co[2], co[3]);
        *(float4*)(h + idx) = make_float4(ho[0], ho[1], ho[2], ho[3]);
        size_t hix = ((size_t)b * TT + t) * DDIM + d;
        *(ushort4*)(H_hi + hix) = make_ushort4(hh4[0], hh4[1], hh4[2], hh4[3]);
        *(ushort4*)(H_lo + hix) = make_ushort4(hl4[0], hl4[1], hl4[2], hl4[3]);
    }
}

// =======================================================================
// host side
// =======================================================================
extern "C" void kernel_launch(void* const* d_in, const int* in_sizes, int n_in,
                              void* d_out, int out_size, void* d_ws, size_t ws_size,
                              hipStream_t stream)
{
    const float* features = (const float*)d_in[0];
    const int*   captions = (const int*)d_in[1];
    const float* embedding= (const float*)d_in[2];
    const float* Wa_w = (const float*)d_in[3];
    const float* Wa_b = (const float*)d_in[4];
    const float* Ua_w = (const float*)d_in[5];
    const float* Ua_b = (const float*)d_in[6];
    const float* Va_w = (const float*)d_in[7];
    const float* Va_b = (const float*)d_in[8];
    const float* W_ih = (const float*)d_in[9];
    const float* W_hh = (const float*)d_in[10];
    const float* b_ih = (const float*)d_in[11];
    const float* b_hh = (const float*)d_in[12];
    const float* ih_w = (const float*)d_in[13];
    const float* ih_b = (const float*)d_in[14];
    const float* ic_w = (const float*)d_in[15];
    const float* ic_b = (const float*)d_in[16];
    const float* fc_w = (const float*)d_in[17];
    const float* fc_b = (const float*)d_in[18];

    float* out_w = (float*)d_out;
    float* out_p = out_w + (size_t)BATCH * TT * NF;

    float* ws = (float*)d_ws;
    size_t off = 0;
    auto alloc = [&](size_t n) { float* p = ws + off; off += n; return p; };

    float* f_proj  = alloc(3211264);
    float* F_ih    = alloc(12845056);
    float* E_ih    = alloc(5505024);
    float* hp_g    = alloc(327680);
    float* mean_f  = alloc(262144);
    float* h       = alloc(65536);
    float* c       = alloc(65536);
    float* bsum    = alloc(2048);
    float* biascat = alloc(2560);
    float* bias_fp = alloc(2560);
    float* bias_hc = alloc(1024);
    u16* feat_hi = (u16*)alloc(6422528);
    u16* feat_lo = (u16*)alloc(6422528);
    u16* emb_hi  = (u16*)alloc(688128);
    u16* emb_lo  = (u16*)alloc(688128);
    u16* H_hi    = (u16*)alloc(688128);
    u16* H_lo    = (u16*)alloc(688128);
    u16* WaWf_hi = (u16*)alloc(2621440);   // 2560 x 2048
    u16* WaWf_lo = (u16*)alloc(2621440);
    u16* We_hi   = (u16*)alloc(524288);    // 2048 x 512
    u16* We_lo   = (u16*)alloc(524288);
    u16* UW_hi   = (u16*)alloc(655360);    // 2560 x 512
    u16* UW_lo   = (u16*)alloc(655360);
    u16* fcw_hi  = (u16*)alloc(3080192);   // 12032 x 512
    u16* fcw_lo  = (u16*)alloc(3080192);

    // ihic (1024 x 2048) split overlays the fc split area until h0c0 GEMM done
    u16* T_hi = fcw_hi;
    u16* T_lo = fcw_lo;

    // ---- init: 5 launches ----
    hipLaunchKernelGGL(mega_split_kernel, dim3(MS_C5 / 256), dim3(256), 0, stream,
                       ih_w, ic_w, Wa_w, W_ih, Ua_w, W_hh, features,
                       b_ih, b_hh, Ua_b, Wa_b, ih_b, ic_b,
                       T_hi, T_lo, WaWf_hi, WaWf_lo, We_hi, We_lo,
                       UW_hi, UW_lo, feat_hi, feat_lo,
                       bsum, biascat, bias_fp, bias_hc);
    hipLaunchKernelGGL(mean_feat_kernel, dim3(BATCH * EDIM / 256), dim3(256), 0, stream,
                       features, mean_f);
    // h0|c0 = mean_f @ [ih_w; ic_w]^T + [ih_b|ic_b]  (N=1024, two-dest)
    hipLaunchKernelGGL(small_mfma_gemm2, dim3(1024 / 8), dim3(256), 0, stream,
                       mean_f, EDIM, T_hi, T_lo, EDIM, bias_hc,
                       h, DDIM, c, DDIM, DDIM);
    // fc split (T overlay now free)
    hipLaunchKernelGGL(split_mat_kernel, dim3((VOCP * DDIM + 255) / 256), dim3(256), 0, stream,
                       fc_w, DDIM, DDIM, VOC, VOCP, fcw_hi, fcw_lo);
    hipLaunchKernelGGL(gather_embed_split_kernel, dim3(BATCH * TT * EMBD / 256), dim3(256), 0, stream,
                       captions, embedding, emb_hi, emb_lo);

    // ---- big GEMMs: 2 launches ----
    // f_proj | F_ih = features @ [Wa_w ; W_ih[:, :E]]^T + [Wa_b | 0]
    {
        dim3 grid(UWN / 128, BATCH * NF / 128);
        hipLaunchKernelGGL(gemm_bf16s2, grid, dim3(256), 0, stream,
                           feat_hi, feat_lo, EDIM, WaWf_hi, WaWf_lo, EDIM,
                           f_proj, DDIM, F_ih, G4, DDIM, bias_fp, UWN, EDIM);
    }
    // E_ih = embeds @ W_ih[:, E:]^T + bsum
    {
        dim3 grid(G4 / 128, BATCH * TT / 128);
        hipLaunchKernelGGL(gemm_bf16s2, grid, dim3(256), 0, stream,
                           emb_hi, emb_lo, EMBD, We_hi, We_lo, EMBD,
                           E_ih, G4, E_ih, G4, G4, bsum, G4, EMBD);
    }

    // ---- sequential loop: 2 launches/step (structural minimum) ----
    for (int t = 0; t < TT; ++t) {
        hipLaunchKernelGGL(small_mfma_gemm2, dim3(UWN / 8), dim3(256), 0, stream,
                           h, DDIM, UW_hi, UW_lo, DDIM, biascat,
                           hp_g, UWN, hp_g, UWN, UWN);
        hipLaunchKernelGGL(fused_step3_kernel, dim3(BATCH * 2), dim3(512), 0, stream,
                           f_proj, hp_g, Va_w, Va_b, F_ih, E_ih, h, c,
                           H_hi, H_lo, out_w, t);
    }

    // ---- preds ----
    {
        dim3 grid(VOCP / 128, BATCH * TT / 128);
        hipLaunchKernelGGL(gemm_bf16s2, grid, dim3(256), 0, stream,
                           H_hi, H_lo, DDIM, fcw_hi, fcw_lo, DDIM,
                           out_p, VOC, out_p, VOC, VOCP, fc_b, VOC, DDIM);
    }
}